// Round 1
// 2754.870 us; speedup vs baseline: 2.1135x; 2.1135x over previous
//
#include <hip/hip_runtime.h>

#define B_  64
#define T_  128
#define BT_ 8192
#define D_  2048
#define H_  1024
#define DD_ 512

typedef unsigned short u16t;
typedef __bf16 bf16x8 __attribute__((ext_vector_type(8)));
typedef float f32x4 __attribute__((ext_vector_type(4)));
typedef unsigned int u32x4 __attribute__((ext_vector_type(4)));

__device__ __forceinline__ u16t f2bf(float f) {
  unsigned u = __float_as_uint(f);
  u += 0x7fffu + ((u >> 16) & 1u);   // round-to-nearest-even
  return (u16t)(u >> 16);
}
__device__ __forceinline__ float bf2f(u16t h) {
  return __uint_as_float(((unsigned)h) << 16);
}
__device__ __forceinline__ float sigm(float x)  { return 1.0f / (1.0f + __expf(-x)); }
__device__ __forceinline__ float tanh_(float x) { return 1.0f - 2.0f / (1.0f + __expf(2.0f * x)); }

// ---------------- system-scope (sc0 sc1) memory ops ----------------
// Bypass L1+L2, coherent at L3 (Infinity Cache) across XCDs. Because BOTH the
// producer stores and consumer loads bypass L2, no buffer_wbl2/buffer_inv cache
// maintenance is ever required — release ordering is a plain s_waitcnt vmcnt(0).
__device__ __forceinline__ bf16x8 ld_coh_b128(const u16t* p) {
  bf16x8 r;
  asm volatile("global_load_dwordx4 %0, %1, off sc0 sc1" : "=v"(r) : "v"(p) : "memory");
  return r;   // NOT ready until a following s_waitcnt vmcnt(0)
}
__device__ __forceinline__ void st_coh_u16(u16t* p, u16t v) {
  asm volatile("global_store_short %0, %1, off sc0 sc1" :: "v"(p), "v"((unsigned)v) : "memory");
}
__device__ __forceinline__ void st_coh_u32(unsigned* p, unsigned v) {
  asm volatile("global_store_dword %0, %1, off sc0 sc1" :: "v"(p), "v"(v) : "memory");
}
__device__ __forceinline__ unsigned ld_coh_u32(const unsigned* p) {
  unsigned r;
  asm volatile("global_load_dword %0, %1, off sc0 sc1" : "=v"(r) : "v"(p) : "memory");
  asm volatile("s_waitcnt vmcnt(0)" ::: "memory");
  return r;
}
__device__ __forceinline__ void waitcnt0() {
  asm volatile("s_waitcnt vmcnt(0)" ::: "memory");
}
// Fence-free 64-block barrier: lane l of each wave watches flag slot l.
__device__ __forceinline__ void wait_flags(const unsigned* fl, unsigned ep) {
  while (true) {
    const unsigned f = ld_coh_u32(fl);
    if (__all((int)(f >= ep))) break;
    __builtin_amdgcn_s_sleep(1);
  }
}

// ---------------- prep kernels ----------------
__global__ void k_prep_bt(const float* __restrict__ x, const float* __restrict__ fi,
                          u16t* __restrict__ bt16) {
  for (size_t i = (size_t)blockIdx.x * blockDim.x + threadIdx.x; i < (size_t)BT_ * D_;
       i += (size_t)gridDim.x * blockDim.x) {
    const size_t r = i >> 11;          // D_ = 2048
    const size_t d = i & (D_ - 1);
    bt16[i] = f2bf(x[i] * (1.0f - fi[(r * 2 + 1) * D_ + d]));
  }
}

__global__ void k_prep_dt(const float* __restrict__ fo, const int* __restrict__ mask,
                          u16t* __restrict__ dt16) {
  for (size_t i = (size_t)blockIdx.x * blockDim.x + threadIdx.x; i < (size_t)BT_ * DD_;
       i += (size_t)gridDim.x * blockDim.x) {
    const size_t r = i >> 9;           // DD_ = 512
    const int jj = (int)(i & (DD_ - 1));
    dt16[i] = f2bf(fo[(r * 2 + 1) * D_ + mask[jj]]);
  }
}

// in [K][N] fp32 -> out [N][K] bf16
__global__ void k_tr_cvt(const float* __restrict__ in, u16t* __restrict__ out, int K, int N) {
  const int total = K * N;
  for (int i = blockIdx.x * blockDim.x + threadIdx.x; i < total; i += gridDim.x * blockDim.x) {
    const int n = i / K;
    const int k = i - n * K;
    out[i] = f2bf(in[(size_t)k * N + n]);
  }
}

// ---------------- MFMA GEMM ----------------
// C[M][N] = A[M][K] * B[K][N] with B given transposed: Bt[N][K], all bf16, fp32 acc.
// mode 0: outb[row*N+col] = bf16(acc + bias[col])
// mode 1: final epilogue: row=(t*64+b) -> out[(b*T+t)*D+col] = sigmoid(acc*(1+At)+eo)
__global__ __launch_bounds__(256) void k_gemm(
    const u16t* __restrict__ A, const u16t* __restrict__ Bt, int N, int K,
    const float* __restrict__ bias, u16t* __restrict__ outb, float* __restrict__ outf,
    const u16t* __restrict__ At16, const float* __restrict__ eo, int mode)
{
  __shared__ __align__(16) u16t As[64 * 32];
  __shared__ __align__(16) u16t Bs[64 * 32];
  const int m0 = blockIdx.x * 64;
  const int n0 = blockIdx.y * 64;
  const int t  = threadIdx.x;
  const int w  = t >> 6;
  const int l  = t & 63;
  const int wr = (w >> 1) * 32;     // wave quadrant row
  const int wc = (w & 1) * 32;      // wave quadrant col
  const int lr = l & 15;
  const int q  = l >> 4;
  const int srow = t >> 2;          // staging: 64 rows x 4 chunks of 8 bf16
  const int sc   = t & 3;
  const int spc  = (sc ^ (srow & 3)) * 8;   // XOR-swizzled physical chunk (store)
  const int rpc  = (q  ^ (lr  & 3)) * 8;    // XOR-swizzled physical chunk (read)

  f32x4 acc00 = {0.f, 0.f, 0.f, 0.f};
  f32x4 acc01 = acc00, acc10 = acc00, acc11 = acc00;
  const u16t* Ap = A  + (size_t)(m0 + srow) * K + sc * 8;
  const u16t* Bp = Bt + (size_t)(n0 + srow) * K + sc * 8;

  for (int k0 = 0; k0 < K; k0 += 32) {
    const u32x4 av = *(const u32x4*)(Ap + k0);
    const u32x4 bv = *(const u32x4*)(Bp + k0);
    __syncthreads();
    *(u32x4*)(As + srow * 32 + spc) = av;
    *(u32x4*)(Bs + srow * 32 + spc) = bv;
    __syncthreads();
    const bf16x8 a0 = *(const bf16x8*)(As + (wr + lr) * 32 + rpc);
    const bf16x8 a1 = *(const bf16x8*)(As + (wr + 16 + lr) * 32 + rpc);
    const bf16x8 b0 = *(const bf16x8*)(Bs + (wc + lr) * 32 + rpc);
    const bf16x8 b1 = *(const bf16x8*)(Bs + (wc + 16 + lr) * 32 + rpc);
    acc00 = __builtin_amdgcn_mfma_f32_16x16x32_bf16(a0, b0, acc00, 0, 0, 0);
    acc01 = __builtin_amdgcn_mfma_f32_16x16x32_bf16(a0, b1, acc01, 0, 0, 0);
    acc10 = __builtin_amdgcn_mfma_f32_16x16x32_bf16(a1, b0, acc10, 0, 0, 0);
    acc11 = __builtin_amdgcn_mfma_f32_16x16x32_bf16(a1, b1, acc11, 0, 0, 0);
  }

  f32x4 accs[2][2] = {{acc00, acc01}, {acc10, acc11}};
  #pragma unroll
  for (int im = 0; im < 2; ++im)
    #pragma unroll
    for (int in = 0; in < 2; ++in)
      #pragma unroll
      for (int r = 0; r < 4; ++r) {
        const int row = m0 + wr + im * 16 + q * 4 + r;   // C/D: row=(lane>>4)*4+reg
        const int col = n0 + wc + in * 16 + lr;          //       col=lane&15
        float v = accs[im][in][r];
        if (mode == 0) {
          if (bias) v += bias[col];
          outb[(size_t)row * N + col] = f2bf(v);
        } else {
          const int tt = row >> 6;        // row = t*64 + b
          const int bb = row & 63;
          const size_t o = ((size_t)bb * T_ + tt) * (size_t)D_ + col;
          outf[o] = sigm(v * (1.0f + bf2f(At16[o])) + eo[col]);
        }
      }
}

// ---------------- recurrence ----------------
// Grid: 256 blocks x 256 threads. block = (row-group g of 16 batch rows) x (col-tile jb of 16).
// Wave w owns K-slice [w*256,(w+1)*256); weight B-frags persistent in VGPRs (96 regs).
// Wave 0 holds exact fp32 h state in MFMA C-layout regs for (rows m0+q*4+r, col j0+lr).
//
// Synchronization (v2): all cross-block traffic (h16/hs16/flags) goes through L3 via
// sc0-sc1 (system-scope) loads/stores that bypass L1+L2 on both sides, so NO
// threadfence / buffer_wbl2 / buffer_inv is needed anywhere. Release = one
// s_waitcnt vmcnt(0) between data stores and the flag store; the barrier is a
// 64-slot flag array polled with one 64-lane load + __all (no atomic chain).
// Own-block flag is set by wave 0 only after it has read red[] — so other waves
// passing the poll can never race wave 0's use of red[].
__global__ __launch_bounds__(256) void k_recur(
    const u16t* __restrict__ pf16, const u16t* __restrict__ ps16, const u16t* __restrict__ pi16,
    const u16t* __restrict__ Wft, const u16t* __restrict__ Wst, const u16t* __restrict__ Wit,
    u16t* __restrict__ h16, u16t* __restrict__ hs16, u16t* __restrict__ hist16,
    unsigned* bar)
{
  __shared__ __align__(16) float red[2 * 4 * 64 * 4];   // [gate][wave][lane][4] = 8 KB
  const int g  = blockIdx.x >> 6;
  const int jb = blockIdx.x & 63;
  const int t  = threadIdx.x;
  const int w  = t >> 6;
  const int l  = t & 63;
  const int lr = l & 15;
  const int q  = l >> 4;
  const int m0 = g * 16;
  const int j0 = jb * 16;
  unsigned* flags = bar + g * 64;       // 64 flag slots per row-group
  const unsigned* myfl = flags + l;     // lane l watches slot l

  // persistent weight fragments: 3 gates x 8 k-chunks x 4 VGPR
  bf16x8 Bf[8], Bs[8], Bi[8];
  {
    const size_t wb = (size_t)(j0 + lr) * H_ + w * 256 + q * 8;
    #pragma unroll
    for (int kc = 0; kc < 8; ++kc) {
      Bf[kc] = *(const bf16x8*)(Wft + wb + (size_t)kc * 32);
      Bs[kc] = *(const bf16x8*)(Wst + wb + (size_t)kc * 32);
      Bi[kc] = *(const bf16x8*)(Wit + wb + (size_t)kc * 32);
    }
  }

  float h_reg[4] = {0.f, 0.f, 0.f, 0.f};
  float f_reg[4] = {0.f, 0.f, 0.f, 0.f};
  unsigned ep = 0;

  // zero this group's rows of h16 (write-through so remote readers see it)
  st_coh_u16(&h16[(size_t)m0 * H_ + jb * 256 + t], (u16t)0);
  waitcnt0();                 // each wave drains its own stores
  __syncthreads();            // all 4 waves' stores are globally visible
  ++ep;
  if (t == 0) st_coh_u32(&flags[jb], ep);
  wait_flags(myfl, ep);

  const size_t arow = (size_t)(m0 + lr) * H_ + w * 256 + q * 8;

  for (int step = 0; step < T_; ++step) {
    // ---- phase A: f, s gates ----
    bf16x8 av[8];
    #pragma unroll
    for (int kc = 0; kc < 8; ++kc) av[kc] = ld_coh_b128(h16 + arow + (size_t)kc * 32);
    float pfv[4], psv[4];
    if (w == 0) {
      #pragma unroll
      for (int r = 0; r < 4; ++r) {
        const size_t prow = ((size_t)(m0 + q * 4 + r) * T_ + step) * H_ + j0 + lr;
        pfv[r] = bf2f(pf16[prow]);
        psv[r] = bf2f(ps16[prow]);
      }
    }
    waitcnt0();
    __builtin_amdgcn_sched_barrier(0);   // keep MFMAs below the waitcnt (rule #18)
    f32x4 accf = {0.f, 0.f, 0.f, 0.f}, accs = accf;
    #pragma unroll
    for (int kc = 0; kc < 8; ++kc) {
      accf = __builtin_amdgcn_mfma_f32_16x16x32_bf16(av[kc], Bf[kc], accf, 0, 0, 0);
      accs = __builtin_amdgcn_mfma_f32_16x16x32_bf16(av[kc], Bs[kc], accs, 0, 0, 0);
    }
    *(f32x4*)&red[(0 * 4 + w) * 256 + l * 4] = accf;
    *(f32x4*)&red[(1 * 4 + w) * 256 + l * 4] = accs;
    __syncthreads();
    ++ep;
    if (w == 0) {
      f32x4 sf = *(const f32x4*)&red[(0 * 4 + 0) * 256 + l * 4];
      f32x4 ss = *(const f32x4*)&red[(1 * 4 + 0) * 256 + l * 4];
      #pragma unroll
      for (int ww = 1; ww < 4; ++ww) {
        sf += *(const f32x4*)&red[(0 * 4 + ww) * 256 + l * 4];
        ss += *(const f32x4*)&red[(1 * 4 + ww) * 256 + l * 4];
      }
      #pragma unroll
      for (int r = 0; r < 4; ++r) {
        const int m = m0 + q * 4 + r;
        const float fv = sigm(pfv[r] + sf[r]);
        const float sv = sigm(psv[r] + ss[r]);
        f_reg[r] = fv;
        st_coh_u16(&hs16[(size_t)m * H_ + j0 + lr], f2bf(h_reg[r] * sv));  // hs = h .* s
      }
      waitcnt0();                               // release: hs visible at L3
      if (l == 0) st_coh_u32(&flags[jb], ep);
    }
    wait_flags(myfl, ep);                       // all waves wait for all 64 hs tiles

    // ---- phase B: c gate + h update ----
    bf16x8 hv[8];
    #pragma unroll
    for (int kc = 0; kc < 8; ++kc) hv[kc] = ld_coh_b128(hs16 + arow + (size_t)kc * 32);
    float piv[4];
    if (w == 0) {
      #pragma unroll
      for (int r = 0; r < 4; ++r) {
        const size_t prow = ((size_t)(m0 + q * 4 + r) * T_ + step) * H_ + j0 + lr;
        piv[r] = bf2f(pi16[prow]);
      }
    }
    waitcnt0();
    __builtin_amdgcn_sched_barrier(0);
    f32x4 acci = {0.f, 0.f, 0.f, 0.f};
    #pragma unroll
    for (int kc = 0; kc < 8; ++kc)
      acci = __builtin_amdgcn_mfma_f32_16x16x32_bf16(hv[kc], Bi[kc], acci, 0, 0, 0);
    *(f32x4*)&red[w * 256 + l * 4] = acci;
    __syncthreads();
    ++ep;
    if (w == 0) {
      f32x4 sc = *(const f32x4*)&red[l * 4];
      #pragma unroll
      for (int ww = 1; ww < 4; ++ww) sc += *(const f32x4*)&red[ww * 256 + l * 4];
      #pragma unroll
      for (int r = 0; r < 4; ++r) {
        const int m = m0 + q * 4 + r;
        const float cv = tanh_(piv[r] + sc[r]);
        h_reg[r] = h_reg[r] * (1.f - f_reg[r]) + f_reg[r] * cv;
        const u16t hb = f2bf(h_reg[r]);
        st_coh_u16(&h16[(size_t)m * H_ + j0 + lr], hb);
        hist16[((size_t)step * B_ + m) * H_ + j0 + lr] = hb;   // kernel-local, normal store
      }
      waitcnt0();                               // release: h visible at L3
      if (l == 0) st_coh_u32(&flags[jb], ep);
    }
    if (step < T_ - 1) wait_flags(myfl, ep);
  }
}

// ---------------- host ----------------
extern "C" void kernel_launch(void* const* d_in, const int* in_sizes, int n_in,
                              void* d_out, int out_size, void* d_ws, size_t ws_size,
                              hipStream_t stream)
{
  const float* x    = (const float*)d_in[0];
  const float* fo   = (const float*)d_in[1];
  const float* fi   = (const float*)d_in[2];
  const float* Wfb  = (const float*)d_in[3];
  const float* Wfa  = (const float*)d_in[4];
  const float* ef   = (const float*)d_in[5];
  const float* Wib  = (const float*)d_in[6];
  const float* Wia  = (const float*)d_in[7];
  const float* ei   = (const float*)d_in[8];
  const float* Wsb  = (const float*)d_in[9];
  const float* Wsa  = (const float*)d_in[10];
  const float* es   = (const float*)d_in[11];
  const float* Wba  = (const float*)d_in[12];
  const float* eo   = (const float*)d_in[13];
  const float* E    = (const float*)d_in[14];
  const int*   mask = (const int*)d_in[15];
  float* out = (float*)d_out;

  char* p = (char*)d_ws;
  auto alloc = [&](size_t bytes) { char* r = p; p += (bytes + 255) & ~(size_t)255; return r; };
  unsigned* bar = (unsigned*)alloc(4096);
  u16t* bt16   = (u16t*)alloc((size_t)BT_ * D_ * 2);
  u16t* dt16   = (u16t*)alloc((size_t)BT_ * DD_ * 2);
  u16t* Wfbt   = (u16t*)alloc((size_t)H_ * D_ * 2);
  u16t* Wsbt   = (u16t*)alloc((size_t)H_ * D_ * 2);
  u16t* Wibt   = (u16t*)alloc((size_t)H_ * D_ * 2);
  u16t* Et     = (u16t*)alloc((size_t)D_ * DD_ * 2);
  u16t* Wbat   = (u16t*)alloc((size_t)D_ * H_ * 2);
  u16t* pf16   = (u16t*)alloc((size_t)BT_ * H_ * 2);
  u16t* ps16   = (u16t*)alloc((size_t)BT_ * H_ * 2);
  u16t* pi16   = (u16t*)alloc((size_t)BT_ * H_ * 2);
  u16t* At16   = (u16t*)alloc((size_t)BT_ * D_ * 2);
  u16t* Wft    = (u16t*)alloc((size_t)H_ * H_ * 2);
  u16t* Wst    = (u16t*)alloc((size_t)H_ * H_ * 2);
  u16t* Wit    = (u16t*)alloc((size_t)H_ * H_ * 2);
  u16t* h16    = (u16t*)alloc((size_t)B_ * H_ * 2);
  u16t* hs16   = (u16t*)alloc((size_t)B_ * H_ * 2);
  u16t* hist16 = (u16t*)alloc((size_t)BT_ * H_ * 2);

  hipMemsetAsync(bar, 0, 4096, stream);

  k_prep_bt<<<4096, 256, 0, stream>>>(x, fi, bt16);
  k_prep_dt<<<2048, 256, 0, stream>>>(fo, mask, dt16);
  k_tr_cvt<<<2048, 256, 0, stream>>>(Wfb, Wfbt, D_, H_);
  k_tr_cvt<<<2048, 256, 0, stream>>>(Wsb, Wsbt, D_, H_);
  k_tr_cvt<<<2048, 256, 0, stream>>>(Wib, Wibt, D_, H_);
  k_tr_cvt<<<1024, 256, 0, stream>>>(E, Et, DD_, D_);
  k_tr_cvt<<<2048, 256, 0, stream>>>(Wba, Wbat, H_, D_);
  k_tr_cvt<<<1024, 256, 0, stream>>>(Wfa, Wft, H_, H_);
  k_tr_cvt<<<1024, 256, 0, stream>>>(Wsa, Wst, H_, H_);
  k_tr_cvt<<<1024, 256, 0, stream>>>(Wia, Wit, H_, H_);

  // pf = bt@Wfb + ef ; ps = bt@Wsb + es ; pi = bt@Wib + ei
  k_gemm<<<dim3(BT_ / 64, H_ / 64), 256, 0, stream>>>(bt16, Wfbt, H_, D_, ef, pf16, nullptr, nullptr, nullptr, 0);
  k_gemm<<<dim3(BT_ / 64, H_ / 64), 256, 0, stream>>>(bt16, Wsbt, H_, D_, es, ps16, nullptr, nullptr, nullptr, 0);
  k_gemm<<<dim3(BT_ / 64, H_ / 64), 256, 0, stream>>>(bt16, Wibt, H_, D_, ei, pi16, nullptr, nullptr, nullptr, 0);
  // At = dt@E
  k_gemm<<<dim3(BT_ / 64, D_ / 64), 256, 0, stream>>>(dt16, Et, D_, DD_, nullptr, At16, nullptr, nullptr, nullptr, 0);

  // sequential recurrence (cooperative; fence-free flag barriers, sc0/sc1 L3
  // communication, MFMA gates, weights persistent in registers)
  void* args[10];
  args[0] = &pf16; args[1] = &ps16; args[2] = &pi16;
  args[3] = &Wft;  args[4] = &Wst;  args[5] = &Wit;
  args[6] = &h16;  args[7] = &hs16; args[8] = &hist16;
  args[9] = &bar;
  hipLaunchCooperativeKernel((void*)k_recur, dim3(256), dim3(256), args, 0, stream);

  // out = sigmoid((h_hist@W_ba) * (1+At) + e_o)
  k_gemm<<<dim3(BT_ / 64, D_ / 64), 256, 0, stream>>>(hist16, Wbat, D_, H_, nullptr, nullptr, out, At16, eo, 1);
}

// Round 3
// 2197.275 us; speedup vs baseline: 2.6499x; 1.2538x over previous
//
#include <hip/hip_runtime.h>

#define B_  64
#define T_  128
#define BT_ 8192
#define D_  2048
#define H_  1024
#define DD_ 512

typedef unsigned short u16t;
typedef __bf16 bf16x8 __attribute__((ext_vector_type(8)));
typedef float f32x4 __attribute__((ext_vector_type(4)));
typedef unsigned int u32x4 __attribute__((ext_vector_type(4)));

__device__ __forceinline__ u16t f2bf(float f) {
  unsigned u = __float_as_uint(f);
  u += 0x7fffu + ((u >> 16) & 1u);   // round-to-nearest-even
  return (u16t)(u >> 16);
}
__device__ __forceinline__ float bf2f(u16t h) {
  return __uint_as_float(((unsigned)h) << 16);
}
__device__ __forceinline__ float sigm(float x)  { return 1.0f / (1.0f + __expf(-x)); }
__device__ __forceinline__ float tanh_(float x) { return 1.0f - 2.0f / (1.0f + __expf(2.0f * x)); }
__device__ __forceinline__ void waitcnt0() {
  asm volatile("s_waitcnt vmcnt(0)" ::: "memory");
}

// ---------------- system-scope (sc0 sc1) memory ops ----------------
// Bypass L1+L2, coherent at L3 (Infinity Cache) across XCDs. Because BOTH the
// producer stores and consumer loads bypass L2, no buffer_wbl2/buffer_inv cache
// maintenance is ever required — release ordering is a plain s_waitcnt vmcnt(0).
__device__ __forceinline__ bf16x8 ld_coh_b128(const u16t* p) {
  bf16x8 r;
  asm volatile("global_load_dwordx4 %0, %1, off sc0 sc1" : "=v"(r) : "v"(p) : "memory");
  return r;   // NOT ready until a following s_waitcnt vmcnt(0)
}
__device__ __forceinline__ void st_coh_u16(u16t* p, u16t v) {
  asm volatile("global_store_short %0, %1, off sc0 sc1" :: "v"(p), "v"((unsigned)v) : "memory");
}
__device__ __forceinline__ void st_coh_u32(unsigned* p, unsigned v) {
  asm volatile("global_store_dword %0, %1, off sc0 sc1" :: "v"(p), "v"(v) : "memory");
}
__device__ __forceinline__ unsigned ld_coh_u32(const unsigned* p) {
  unsigned r;
  asm volatile("global_load_dword %0, %1, off sc0 sc1" : "=v"(r) : "v"(p) : "memory");
  asm volatile("s_waitcnt vmcnt(0)" ::: "memory");
  return r;
}
// Wave-0-only barrier wait: lane l watches flag slot l (64 packed dwords/group).
__device__ __forceinline__ void wait_flags64(const unsigned* fl, unsigned ep) {
  const unsigned* p = fl + (threadIdx.x & 63);
  while (true) {
    const unsigned f = ld_coh_u32(p);
    if (__all((int)(f >= ep))) break;
    __builtin_amdgcn_s_sleep(1);
  }
}

// ---------------- prep kernels ----------------
__global__ void k_prep_bt(const float* __restrict__ x, const float* __restrict__ fi,
                          u16t* __restrict__ bt16) {
  for (size_t i = (size_t)blockIdx.x * blockDim.x + threadIdx.x; i < (size_t)BT_ * D_;
       i += (size_t)gridDim.x * blockDim.x) {
    const size_t r = i >> 11;          // D_ = 2048
    const size_t d = i & (D_ - 1);
    bt16[i] = f2bf(x[i] * (1.0f - fi[(r * 2 + 1) * D_ + d]));
  }
}

__global__ void k_prep_dt(const float* __restrict__ fo, const int* __restrict__ mask,
                          u16t* __restrict__ dt16) {
  for (size_t i = (size_t)blockIdx.x * blockDim.x + threadIdx.x; i < (size_t)BT_ * DD_;
       i += (size_t)gridDim.x * blockDim.x) {
    const size_t r = i >> 9;           // DD_ = 512
    const int jj = (int)(i & (DD_ - 1));
    dt16[i] = f2bf(fo[(r * 2 + 1) * D_ + mask[jj]]);
  }
}

// in [K][N] fp32 -> out [N][K] bf16
__global__ void k_tr_cvt(const float* __restrict__ in, u16t* __restrict__ out, int K, int N) {
  const int total = K * N;
  for (int i = blockIdx.x * blockDim.x + threadIdx.x; i < total; i += gridDim.x * blockDim.x) {
    const int n = i / K;
    const int k = i - n * K;
    out[i] = f2bf(in[(size_t)k * N + n]);
  }
}

// ---------------- MFMA GEMM ----------------
// C[M][N] = A[M][K] * B[K][N] with B given transposed: Bt[N][K], all bf16, fp32 acc.
// mode 0: outb[row*N+col] = bf16(acc + bias[col])
// mode 1: final epilogue: row=(t*64+b) -> out[(b*T+t)*D+col] = sigmoid(acc*(1+At)+eo)
__global__ __launch_bounds__(256) void k_gemm(
    const u16t* __restrict__ A, const u16t* __restrict__ Bt, int N, int K,
    const float* __restrict__ bias, u16t* __restrict__ outb, float* __restrict__ outf,
    const u16t* __restrict__ At16, const float* __restrict__ eo, int mode)
{
  __shared__ __align__(16) u16t As[64 * 32];
  __shared__ __align__(16) u16t Bs[64 * 32];
  const int m0 = blockIdx.x * 64;
  const int n0 = blockIdx.y * 64;
  const int t  = threadIdx.x;
  const int w  = t >> 6;
  const int l  = t & 63;
  const int wr = (w >> 1) * 32;     // wave quadrant row
  const int wc = (w & 1) * 32;      // wave quadrant col
  const int lr = l & 15;
  const int q  = l >> 4;
  const int srow = t >> 2;          // staging: 64 rows x 4 chunks of 8 bf16
  const int sc   = t & 3;
  const int spc  = (sc ^ (srow & 3)) * 8;   // XOR-swizzled physical chunk (store)
  const int rpc  = (q  ^ (lr  & 3)) * 8;    // XOR-swizzled physical chunk (read)

  f32x4 acc00 = {0.f, 0.f, 0.f, 0.f};
  f32x4 acc01 = acc00, acc10 = acc00, acc11 = acc00;
  const u16t* Ap = A  + (size_t)(m0 + srow) * K + sc * 8;
  const u16t* Bp = Bt + (size_t)(n0 + srow) * K + sc * 8;

  for (int k0 = 0; k0 < K; k0 += 32) {
    const u32x4 av = *(const u32x4*)(Ap + k0);
    const u32x4 bv = *(const u32x4*)(Bp + k0);
    __syncthreads();
    *(u32x4*)(As + srow * 32 + spc) = av;
    *(u32x4*)(Bs + srow * 32 + spc) = bv;
    __syncthreads();
    const bf16x8 a0 = *(const bf16x8*)(As + (wr + lr) * 32 + rpc);
    const bf16x8 a1 = *(const bf16x8*)(As + (wr + 16 + lr) * 32 + rpc);
    const bf16x8 b0 = *(const bf16x8*)(Bs + (wc + lr) * 32 + rpc);
    const bf16x8 b1 = *(const bf16x8*)(Bs + (wc + 16 + lr) * 32 + rpc);
    acc00 = __builtin_amdgcn_mfma_f32_16x16x32_bf16(a0, b0, acc00, 0, 0, 0);
    acc01 = __builtin_amdgcn_mfma_f32_16x16x32_bf16(a0, b1, acc01, 0, 0, 0);
    acc10 = __builtin_amdgcn_mfma_f32_16x16x32_bf16(a1, b0, acc10, 0, 0, 0);
    acc11 = __builtin_amdgcn_mfma_f32_16x16x32_bf16(a1, b1, acc11, 0, 0, 0);
  }

  f32x4 accs[2][2] = {{acc00, acc01}, {acc10, acc11}};
  #pragma unroll
  for (int im = 0; im < 2; ++im)
    #pragma unroll
    for (int in = 0; in < 2; ++in)
      #pragma unroll
      for (int r = 0; r < 4; ++r) {
        const int row = m0 + wr + im * 16 + q * 4 + r;   // C/D: row=(lane>>4)*4+reg
        const int col = n0 + wc + in * 16 + lr;          //       col=lane&15
        float v = accs[im][in][r];
        if (mode == 0) {
          if (bias) v += bias[col];
          outb[(size_t)row * N + col] = f2bf(v);
        } else {
          const int tt = row >> 6;        // row = t*64 + b
          const int bb = row & 63;
          const size_t o = ((size_t)bb * T_ + tt) * (size_t)D_ + col;
          outf[o] = sigm(v * (1.0f + bf2f(At16[o])) + eo[col]);
        }
      }
}

// ---------------- recurrence ----------------
// Grid: 256 blocks x 256 threads. block = (row-group g of 16 batch rows) x (col-tile jb of 16).
// Wave w owns K-slice [w*256,(w+1)*256); weight B-frags persistent in VGPRs (96 regs).
// Wave 0 holds exact fp32 h state in MFMA C-layout regs for (rows m0+q*4+r, col j0+lr).
//
// Sync (v3 = de-risked v2): identical sc0sc1/L3 protocol to the verified R1 kernel,
// with two changes only:
//  (a) only wave 0 polls the 64 flag slots (4x less sc-load pressure on the flag
//      lines; waves 1-3 are released by __syncthreads), and
//  (b) hist16 stores are issued after the flag store (HBM ack off critical path).
__global__ __launch_bounds__(256) void k_recur(
    const u16t* __restrict__ pf16, const u16t* __restrict__ ps16, const u16t* __restrict__ pi16,
    const u16t* __restrict__ Wft, const u16t* __restrict__ Wst, const u16t* __restrict__ Wit,
    u16t* __restrict__ h16, u16t* __restrict__ hs16, u16t* __restrict__ hist16,
    unsigned* bar)
{
  __shared__ __align__(16) float red[2 * 4 * 64 * 4];   // [gate][wave][lane][4] = 8 KB
  const int g  = blockIdx.x >> 6;
  const int jb = blockIdx.x & 63;
  const int t  = threadIdx.x;
  const int w  = t >> 6;
  const int l  = t & 63;
  const int lr = l & 15;
  const int q  = l >> 4;
  const int m0 = g * 16;
  const int j0 = jb * 16;
  unsigned* flags = bar + g * 64;       // 64 flag slots per row-group

  // persistent weight fragments: 3 gates x 8 k-chunks x 4 VGPR
  bf16x8 Bf[8], Bs[8], Bi[8];
  {
    const size_t wb = (size_t)(j0 + lr) * H_ + w * 256 + q * 8;
    #pragma unroll
    for (int kc = 0; kc < 8; ++kc) {
      Bf[kc] = *(const bf16x8*)(Wft + wb + (size_t)kc * 32);
      Bs[kc] = *(const bf16x8*)(Wst + wb + (size_t)kc * 32);
      Bi[kc] = *(const bf16x8*)(Wit + wb + (size_t)kc * 32);
    }
  }

  float h_reg[4] = {0.f, 0.f, 0.f, 0.f};
  float f_reg[4] = {0.f, 0.f, 0.f, 0.f};
  unsigned ep = 0;

  // zero this group's rows of h16 (write-through so remote readers see it)
  st_coh_u16(&h16[(size_t)m0 * H_ + jb * 256 + t], (u16t)0);
  waitcnt0();                 // each wave drains its own stores
  __syncthreads();            // all 4 waves' stores are globally visible
  ++ep;
  if (w == 0) {
    if (l == 0) st_coh_u32(&flags[jb], ep);
    wait_flags64(flags, ep);
  }
  __syncthreads();

  const size_t arow = (size_t)(m0 + lr) * H_ + w * 256 + q * 8;

  for (int step = 0; step < T_; ++step) {
    // ---- phase A: f, s gates ----
    bf16x8 av[8];
    #pragma unroll
    for (int kc = 0; kc < 8; ++kc) av[kc] = ld_coh_b128(h16 + arow + (size_t)kc * 32);
    float pfv[4], psv[4];
    if (w == 0) {
      #pragma unroll
      for (int r = 0; r < 4; ++r) {
        const size_t prow = ((size_t)(m0 + q * 4 + r) * T_ + step) * H_ + j0 + lr;
        pfv[r] = bf2f(pf16[prow]);
        psv[r] = bf2f(ps16[prow]);
      }
    }
    waitcnt0();
    __builtin_amdgcn_sched_barrier(0);   // keep MFMAs below the waitcnt (rule #18)
    f32x4 accf = {0.f, 0.f, 0.f, 0.f}, accs = accf;
    #pragma unroll
    for (int kc = 0; kc < 8; ++kc) {
      accf = __builtin_amdgcn_mfma_f32_16x16x32_bf16(av[kc], Bf[kc], accf, 0, 0, 0);
      accs = __builtin_amdgcn_mfma_f32_16x16x32_bf16(av[kc], Bs[kc], accs, 0, 0, 0);
    }
    *(f32x4*)&red[(0 * 4 + w) * 256 + l * 4] = accf;
    *(f32x4*)&red[(1 * 4 + w) * 256 + l * 4] = accs;
    __syncthreads();
    ++ep;
    if (w == 0) {
      f32x4 sf = *(const f32x4*)&red[(0 * 4 + 0) * 256 + l * 4];
      f32x4 ss = *(const f32x4*)&red[(1 * 4 + 0) * 256 + l * 4];
      #pragma unroll
      for (int ww = 1; ww < 4; ++ww) {
        sf += *(const f32x4*)&red[(0 * 4 + ww) * 256 + l * 4];
        ss += *(const f32x4*)&red[(1 * 4 + ww) * 256 + l * 4];
      }
      #pragma unroll
      for (int r = 0; r < 4; ++r) {
        const int m = m0 + q * 4 + r;
        const float fv = sigm(pfv[r] + sf[r]);
        const float sv = sigm(psv[r] + ss[r]);
        f_reg[r] = fv;
        st_coh_u16(&hs16[(size_t)m * H_ + j0 + lr], f2bf(h_reg[r] * sv));  // hs = h .* s
      }
      waitcnt0();                               // release: hs visible at L3
      if (l == 0) st_coh_u32(&flags[jb], ep);
      wait_flags64(flags, ep);                  // wave 0 waits for all 64 hs tiles
    }
    __syncthreads();

    // ---- phase B: c gate + h update ----
    bf16x8 hv[8];
    #pragma unroll
    for (int kc = 0; kc < 8; ++kc) hv[kc] = ld_coh_b128(hs16 + arow + (size_t)kc * 32);
    float piv[4];
    if (w == 0) {
      #pragma unroll
      for (int r = 0; r < 4; ++r) {
        const size_t prow = ((size_t)(m0 + q * 4 + r) * T_ + step) * H_ + j0 + lr;
        piv[r] = bf2f(pi16[prow]);
      }
    }
    waitcnt0();
    __builtin_amdgcn_sched_barrier(0);
    f32x4 acci = {0.f, 0.f, 0.f, 0.f};
    #pragma unroll
    for (int kc = 0; kc < 8; ++kc)
      acci = __builtin_amdgcn_mfma_f32_16x16x32_bf16(hv[kc], Bi[kc], acci, 0, 0, 0);
    *(f32x4*)&red[w * 256 + l * 4] = acci;
    __syncthreads();
    ++ep;
    if (w == 0) {
      f32x4 sc = *(const f32x4*)&red[l * 4];
      #pragma unroll
      for (int ww = 1; ww < 4; ++ww) sc += *(const f32x4*)&red[ww * 256 + l * 4];
      u16t hbv[4];
      #pragma unroll
      for (int r = 0; r < 4; ++r) {
        const int m = m0 + q * 4 + r;
        const float cv = tanh_(piv[r] + sc[r]);
        h_reg[r] = h_reg[r] * (1.f - f_reg[r]) + f_reg[r] * cv;
        hbv[r] = f2bf(h_reg[r]);
        st_coh_u16(&h16[(size_t)m * H_ + j0 + lr], hbv[r]);
      }
      waitcnt0();                               // release: h visible at L3
      if (l == 0) st_coh_u32(&flags[jb], ep);
      // history writes off the critical path (after the flag store)
      #pragma unroll
      for (int r = 0; r < 4; ++r)
        hist16[((size_t)step * B_ + (m0 + q * 4 + r)) * H_ + j0 + lr] = hbv[r];
      if (step < T_ - 1) wait_flags64(flags, ep);
    }
    __syncthreads();
  }
}

// ---------------- host ----------------
extern "C" void kernel_launch(void* const* d_in, const int* in_sizes, int n_in,
                              void* d_out, int out_size, void* d_ws, size_t ws_size,
                              hipStream_t stream)
{
  const float* x    = (const float*)d_in[0];
  const float* fo   = (const float*)d_in[1];
  const float* fi   = (const float*)d_in[2];
  const float* Wfb  = (const float*)d_in[3];
  const float* Wfa  = (const float*)d_in[4];
  const float* ef   = (const float*)d_in[5];
  const float* Wib  = (const float*)d_in[6];
  const float* Wia  = (const float*)d_in[7];
  const float* ei   = (const float*)d_in[8];
  const float* Wsb  = (const float*)d_in[9];
  const float* Wsa  = (const float*)d_in[10];
  const float* es   = (const float*)d_in[11];
  const float* Wba  = (const float*)d_in[12];
  const float* eo   = (const float*)d_in[13];
  const float* E    = (const float*)d_in[14];
  const int*   mask = (const int*)d_in[15];
  float* out = (float*)d_out;

  char* p = (char*)d_ws;
  auto alloc = [&](size_t bytes) { char* r = p; p += (bytes + 255) & ~(size_t)255; return r; };
  unsigned* bar = (unsigned*)alloc(4096);
  u16t* bt16   = (u16t*)alloc((size_t)BT_ * D_ * 2);
  u16t* dt16   = (u16t*)alloc((size_t)BT_ * DD_ * 2);
  u16t* Wfbt   = (u16t*)alloc((size_t)H_ * D_ * 2);
  u16t* Wsbt   = (u16t*)alloc((size_t)H_ * D_ * 2);
  u16t* Wibt   = (u16t*)alloc((size_t)H_ * D_ * 2);
  u16t* Et     = (u16t*)alloc((size_t)D_ * DD_ * 2);
  u16t* Wbat   = (u16t*)alloc((size_t)D_ * H_ * 2);
  u16t* pf16   = (u16t*)alloc((size_t)BT_ * H_ * 2);
  u16t* ps16   = (u16t*)alloc((size_t)BT_ * H_ * 2);
  u16t* pi16   = (u16t*)alloc((size_t)BT_ * H_ * 2);
  u16t* At16   = (u16t*)alloc((size_t)BT_ * D_ * 2);
  u16t* Wft    = (u16t*)alloc((size_t)H_ * H_ * 2);
  u16t* Wst    = (u16t*)alloc((size_t)H_ * H_ * 2);
  u16t* Wit    = (u16t*)alloc((size_t)H_ * H_ * 2);
  u16t* h16    = (u16t*)alloc((size_t)B_ * H_ * 2);
  u16t* hs16   = (u16t*)alloc((size_t)B_ * H_ * 2);
  u16t* hist16 = (u16t*)alloc((size_t)BT_ * H_ * 2);

  hipMemsetAsync(bar, 0, 4096, stream);

  k_prep_bt<<<4096, 256, 0, stream>>>(x, fi, bt16);
  k_prep_dt<<<2048, 256, 0, stream>>>(fo, mask, dt16);
  k_tr_cvt<<<2048, 256, 0, stream>>>(Wfb, Wfbt, D_, H_);
  k_tr_cvt<<<2048, 256, 0, stream>>>(Wsb, Wsbt, D_, H_);
  k_tr_cvt<<<2048, 256, 0, stream>>>(Wib, Wibt, D_, H_);
  k_tr_cvt<<<1024, 256, 0, stream>>>(E, Et, DD_, D_);
  k_tr_cvt<<<2048, 256, 0, stream>>>(Wba, Wbat, H_, D_);
  k_tr_cvt<<<1024, 256, 0, stream>>>(Wfa, Wft, H_, H_);
  k_tr_cvt<<<1024, 256, 0, stream>>>(Wsa, Wst, H_, H_);
  k_tr_cvt<<<1024, 256, 0, stream>>>(Wia, Wit, H_, H_);

  // pf = bt@Wfb + ef ; ps = bt@Wsb + es ; pi = bt@Wib + ei
  k_gemm<<<dim3(BT_ / 64, H_ / 64), 256, 0, stream>>>(bt16, Wfbt, H_, D_, ef, pf16, nullptr, nullptr, nullptr, 0);
  k_gemm<<<dim3(BT_ / 64, H_ / 64), 256, 0, stream>>>(bt16, Wsbt, H_, D_, es, ps16, nullptr, nullptr, nullptr, 0);
  k_gemm<<<dim3(BT_ / 64, H_ / 64), 256, 0, stream>>>(bt16, Wibt, H_, D_, ei, pi16, nullptr, nullptr, nullptr, 0);
  // At = dt@E
  k_gemm<<<dim3(BT_ / 64, D_ / 64), 256, 0, stream>>>(dt16, Et, D_, DD_, nullptr, At16, nullptr, nullptr, nullptr, 0);

  // sequential recurrence (cooperative; fence-free flag barriers, sc0/sc1 L3
  // communication, MFMA gates, weights persistent in registers)
  void* args[10];
  args[0] = &pf16; args[1] = &ps16; args[2] = &pi16;
  args[3] = &Wft;  args[4] = &Wst;  args[5] = &Wit;
  args[6] = &h16;  args[7] = &hs16; args[8] = &hist16;
  args[9] = &bar;
  hipLaunchCooperativeKernel((void*)k_recur, dim3(256), dim3(256), args, 0, stream);

  // out = sigmoid((h_hist@W_ba) * (1+At) + e_o)
  k_gemm<<<dim3(BT_ / 64, D_ / 64), 256, 0, stream>>>(hist16, Wbat, D_, H_, nullptr, nullptr, out, At16, eo, 1);
}